// Round 1
// baseline (189.129 us; speedup 1.0000x reference)
//
#include <hip/hip_runtime.h>
#include <math.h>

// VQ-VAE VectorQuantizer: B=32,T=2048,D=64,K=1024  -> N=65536 rows.
// Outputs (flat f32 in d_out): quantized_st [N*64], indices [N], vq_loss,
// e_latent_loss, codebook_loss.
//
// Round 1: exact-fp32 baseline that replicates numpy float32 semantics so the
// argmin matches the np reference bitwise-ish:
//  - sum(x*x) / sum(e*e): numpy pairwise 8-accumulator pattern for n=64
//  - dot: sequential-k FMA (BLAS sgemm microkernel order)
//  - dist = fl(fl(sx+se_j) - 2*dot), argmin = first strict min
//  - fp contract OFF everywhere except the explicit fmaf chain
// K is partitioned 4-ways across blocks for 4 waves/SIMD (dependent FMA chain
// at 4-cyc latency needs >=2 waves/SIMD to saturate VALU issue).

namespace {
constexpr int NROWS = 65536;
constexpr int DDIM  = 64;
constexpr int KCODES = 1024;
constexpr int KPART = 4;
constexpr int CPP = KCODES / KPART;   // codes per partition = 256

// ws layout (bytes)
constexpr size_t WS_LOSS = 0;                                   // double
constexpr size_t WS_SE   = 256;                                 // float[K]
constexpr size_t WS_BVAL = 8192;                                // float[KPART*N]
constexpr size_t WS_BIDX = WS_BVAL + (size_t)KPART * NROWS * 4; // int[KPART*N]
}

// ---------------- prep: se[j] = np.sum(e*e, axis=1) (numpy pairwise), zero loss
__global__ __launch_bounds__(256) void vq_prep(const float* __restrict__ emb,
                                               float* __restrict__ se,
                                               double* __restrict__ loss_accum) {
  #pragma clang fp contract(off)
  const int t = blockIdx.x * 256 + threadIdx.x;
  if (t == 0) *loss_accum = 0.0;
  if (t < KCODES) {
    const float* e = emb + (size_t)t * DDIM;
    float r[8];
    #pragma unroll
    for (int j = 0; j < 8; ++j) r[j] = e[j] * e[j];
    #pragma unroll
    for (int i = 8; i < DDIM; i += 8) {
      #pragma unroll
      for (int j = 0; j < 8; ++j) r[j] += e[i + j] * e[i + j];
    }
    se[t] = ((r[0] + r[1]) + (r[2] + r[3])) + ((r[4] + r[5]) + (r[6] + r[7]));
  }
}

// ---------------- main: per-row argmin over a K/4 partition
__global__ __launch_bounds__(256) void vq_argmin(const float* __restrict__ x,
                                                 const float* __restrict__ emb,
                                                 const float* __restrict__ se,
                                                 float* __restrict__ bval,
                                                 int* __restrict__ bidx) {
  #pragma clang fp contract(off)
  const int part = blockIdx.x & (KPART - 1);
  const int rowgroup = blockIdx.x >> 2;
  const int row = rowgroup * 256 + (int)threadIdx.x;

  const float* xr = x + (size_t)row * DDIM;
  float xv[DDIM];
  #pragma unroll
  for (int d = 0; d < DDIM; d += 4) {
    const float4 v = *reinterpret_cast<const float4*>(xr + d);
    xv[d] = v.x; xv[d + 1] = v.y; xv[d + 2] = v.z; xv[d + 3] = v.w;
  }

  // ||x||^2 with numpy pairwise 8-accumulator order (row-constant, but keep
  // it bit-identical to np so the (sx+se_j) rounding pattern matches).
  float r[8];
  #pragma unroll
  for (int j = 0; j < 8; ++j) r[j] = xv[j] * xv[j];
  #pragma unroll
  for (int i = 8; i < DDIM; i += 8) {
    #pragma unroll
    for (int j = 0; j < 8; ++j) r[j] += xv[i + j] * xv[i + j];
  }
  const float sx = ((r[0] + r[1]) + (r[2] + r[3])) + ((r[4] + r[5]) + (r[6] + r[7]));

  float best = INFINITY;
  int   bi   = 0;
  const int j0 = part * CPP;
  for (int jj = 0; jj < CPP; ++jj) {
    const int j = j0 + jj;
    const float* ep = emb + (size_t)j * DDIM;  // wave-uniform -> s_load
    float acc = 0.0f;
    #pragma unroll
    for (int d = 0; d < DDIM; ++d) acc = __builtin_fmaf(xv[d], ep[d], acc);
    const float T = sx + se[j];          // fl(sx + se_j)
    const float dist = T - 2.0f * acc;   // 2*acc exact; one rounding
    if (dist < best) { best = dist; bi = j; }  // strict < -> first min
  }
  bval[(size_t)part * NROWS + row] = best;
  bidx[(size_t)part * NROWS + row] = bi;
}

// ---------------- finalize: combine partitions, gather, ST output, loss
__global__ __launch_bounds__(256) void vq_finalize(const float* __restrict__ x,
                                                   const float* __restrict__ emb,
                                                   const float* __restrict__ bval,
                                                   const int* __restrict__ bidx,
                                                   float* __restrict__ out,
                                                   double* __restrict__ loss_accum) {
  #pragma clang fp contract(off)
  const int row = blockIdx.x * 256 + (int)threadIdx.x;

  float best = bval[row];
  int   bi   = bidx[row];
  #pragma unroll
  for (int p = 1; p < KPART; ++p) {
    const float v = bval[(size_t)p * NROWS + row];
    const int   i = bidx[(size_t)p * NROWS + row];
    if (v < best) { best = v; bi = i; }  // ties keep lower partition (lower j)
  }

  const float* xr = x + (size_t)row * DDIM;
  const float* ep = emb + (size_t)bi * DDIM;
  float* orow = out + (size_t)row * DDIM;
  float lsum = 0.0f;
  #pragma unroll
  for (int d = 0; d < DDIM; ++d) {
    const float xd = xr[d];
    const float q  = ep[d];
    const float diff = q - xd;     // fl(q - x)
    orow[d] = xd + diff;           // straight-through: fl(x + fl(q - x))
    lsum += diff * diff;           // (q - x)^2, order-insensitive (2% thr)
  }

  out[(size_t)NROWS * DDIM + row] = (float)bi;  // index as f32 (exact <= 1023)

  #pragma unroll
  for (int off = 32; off > 0; off >>= 1) lsum += __shfl_down(lsum, off, 64);
  if ((threadIdx.x & 63) == 0) atomicAdd(loss_accum, (double)lsum);
}

// ---------------- scalars
__global__ void vq_scalars(const double* __restrict__ loss_accum,
                           float* __restrict__ out) {
  if (threadIdx.x == 0 && blockIdx.x == 0) {
    const double m = *loss_accum / (double)((size_t)NROWS * DDIM);
    const float el = (float)m;
    float* tail = out + (size_t)NROWS * DDIM + NROWS;
    tail[0] = 0.25f * el;  // vq_loss = COMMITMENT_COST * e_latent_loss
    tail[1] = el;          // e_latent_loss
    tail[2] = 0.0f;        // codebook_loss
  }
}

extern "C" void kernel_launch(void* const* d_in, const int* in_sizes, int n_in,
                              void* d_out, int out_size, void* d_ws, size_t ws_size,
                              hipStream_t stream) {
  const float* x   = (const float*)d_in[0];  // [N, 64]
  const float* emb = (const float*)d_in[1];  // [K, 64]
  float* out = (float*)d_out;

  char* ws = (char*)d_ws;
  double* loss_accum = (double*)(ws + WS_LOSS);
  float*  se         = (float*)(ws + WS_SE);
  float*  bval       = (float*)(ws + WS_BVAL);
  int*    bidx       = (int*)(ws + WS_BIDX);

  vq_prep<<<KCODES / 256, 256, 0, stream>>>(emb, se, loss_accum);
  vq_argmin<<<(NROWS / 256) * KPART, 256, 0, stream>>>(x, emb, se, bval, bidx);
  vq_finalize<<<NROWS / 256, 256, 0, stream>>>(x, emb, bval, bidx, out, loss_accum);
  vq_scalars<<<1, 64, 0, stream>>>(loss_accum, out);
}

// Round 2
// 188.710 us; speedup vs baseline: 1.0022x; 1.0022x over previous
//
#include <hip/hip_runtime.h>
#include <math.h>

// VQ-VAE VectorQuantizer: B=32,T=2048,D=64,K=1024  -> N=65536 rows.
// Outputs (flat f32 in d_out): quantized_st [N*64], indices [N], vq_loss,
// e_latent_loss, codebook_loss.
//
// Round 2: same exact-fp32 numpy-emulating structure as round 1 (absmax 0.0),
// plus:
//  - __launch_bounds__(256, 2) on vq_argmin: round 1's VGPR_Count=40 showed
//    the compiler demoted xv[64] to AGPRs (default ~8 waves/SIMD heuristic
//    caps arch VGPRs at 64); every FMA then paid a v_accvgpr_read -> 2.3
//    VALU slots per FMA (measured 125us issue vs 54.6us pure-FMA floor).
//    Budget 256 VGPR keeps xv resident; ~84 VGPR -> 6 waves/SIMD natural.
//  - dist = fmaf(-2, acc, T): bit-identical to T - 2*acc (2*acc is exact,
//    single rounding either way), one less VALU per code.

namespace {
constexpr int NROWS = 65536;
constexpr int DDIM  = 64;
constexpr int KCODES = 1024;
constexpr int KPART = 4;
constexpr int CPP = KCODES / KPART;   // codes per partition = 256

// ws layout (bytes)
constexpr size_t WS_LOSS = 0;                                   // double
constexpr size_t WS_SE   = 256;                                 // float[K]
constexpr size_t WS_BVAL = 8192;                                // float[KPART*N]
constexpr size_t WS_BIDX = WS_BVAL + (size_t)KPART * NROWS * 4; // int[KPART*N]
}

// ---------------- prep: se[j] = np.sum(e*e, axis=1) (numpy pairwise), zero loss
__global__ __launch_bounds__(256) void vq_prep(const float* __restrict__ emb,
                                               float* __restrict__ se,
                                               double* __restrict__ loss_accum) {
  #pragma clang fp contract(off)
  const int t = blockIdx.x * 256 + threadIdx.x;
  if (t == 0) *loss_accum = 0.0;
  if (t < KCODES) {
    const float* e = emb + (size_t)t * DDIM;
    float r[8];
    #pragma unroll
    for (int j = 0; j < 8; ++j) r[j] = e[j] * e[j];
    #pragma unroll
    for (int i = 8; i < DDIM; i += 8) {
      #pragma unroll
      for (int j = 0; j < 8; ++j) r[j] += e[i + j] * e[i + j];
    }
    se[t] = ((r[0] + r[1]) + (r[2] + r[3])) + ((r[4] + r[5]) + (r[6] + r[7]));
  }
}

// ---------------- main: per-row argmin over a K/4 partition
__global__ __launch_bounds__(256, 2) void vq_argmin(const float* __restrict__ x,
                                                    const float* __restrict__ emb,
                                                    const float* __restrict__ se,
                                                    float* __restrict__ bval,
                                                    int* __restrict__ bidx) {
  #pragma clang fp contract(off)
  const int part = blockIdx.x & (KPART - 1);
  const int rowgroup = blockIdx.x >> 2;
  const int row = rowgroup * 256 + (int)threadIdx.x;

  const float* xr = x + (size_t)row * DDIM;
  float xv[DDIM];
  #pragma unroll
  for (int d = 0; d < DDIM; d += 4) {
    const float4 v = *reinterpret_cast<const float4*>(xr + d);
    xv[d] = v.x; xv[d + 1] = v.y; xv[d + 2] = v.z; xv[d + 3] = v.w;
  }

  // ||x||^2 with numpy pairwise 8-accumulator order (row-constant, but keep
  // it bit-identical to np so the (sx+se_j) rounding pattern matches).
  float r[8];
  #pragma unroll
  for (int j = 0; j < 8; ++j) r[j] = xv[j] * xv[j];
  #pragma unroll
  for (int i = 8; i < DDIM; i += 8) {
    #pragma unroll
    for (int j = 0; j < 8; ++j) r[j] += xv[i + j] * xv[i + j];
  }
  const float sx = ((r[0] + r[1]) + (r[2] + r[3])) + ((r[4] + r[5]) + (r[6] + r[7]));

  float best = INFINITY;
  int   bi   = 0;
  const int j0 = part * CPP;
  for (int jj = 0; jj < CPP; ++jj) {
    const int j = j0 + jj;
    const float* ep = emb + (size_t)j * DDIM;  // wave-uniform -> s_load
    float acc = 0.0f;
    #pragma unroll
    for (int d = 0; d < DDIM; ++d) acc = __builtin_fmaf(xv[d], ep[d], acc);
    const float T = sx + se[j];                       // fl(sx + se_j)
    const float dist = __builtin_fmaf(-2.0f, acc, T); // == fl(T - 2*acc), 2*acc exact
    if (dist < best) { best = dist; bi = j; }  // strict < -> first min
  }
  bval[(size_t)part * NROWS + row] = best;
  bidx[(size_t)part * NROWS + row] = bi;
}

// ---------------- finalize: combine partitions, gather, ST output, loss
__global__ __launch_bounds__(256) void vq_finalize(const float* __restrict__ x,
                                                   const float* __restrict__ emb,
                                                   const float* __restrict__ bval,
                                                   const int* __restrict__ bidx,
                                                   float* __restrict__ out,
                                                   double* __restrict__ loss_accum) {
  #pragma clang fp contract(off)
  const int row = blockIdx.x * 256 + (int)threadIdx.x;

  float best = bval[row];
  int   bi   = bidx[row];
  #pragma unroll
  for (int p = 1; p < KPART; ++p) {
    const float v = bval[(size_t)p * NROWS + row];
    const int   i = bidx[(size_t)p * NROWS + row];
    if (v < best) { best = v; bi = i; }  // ties keep lower partition (lower j)
  }

  const float* xr = x + (size_t)row * DDIM;
  const float* ep = emb + (size_t)bi * DDIM;
  float* orow = out + (size_t)row * DDIM;
  float lsum = 0.0f;
  #pragma unroll
  for (int d = 0; d < DDIM; ++d) {
    const float xd = xr[d];
    const float q  = ep[d];
    const float diff = q - xd;     // fl(q - x)
    orow[d] = xd + diff;           // straight-through: fl(x + fl(q - x))
    lsum += diff * diff;           // (q - x)^2, order-insensitive (2% thr)
  }

  out[(size_t)NROWS * DDIM + row] = (float)bi;  // index as f32 (exact <= 1023)

  #pragma unroll
  for (int off = 32; off > 0; off >>= 1) lsum += __shfl_down(lsum, off, 64);
  if ((threadIdx.x & 63) == 0) atomicAdd(loss_accum, (double)lsum);
}

// ---------------- scalars
__global__ void vq_scalars(const double* __restrict__ loss_accum,
                           float* __restrict__ out) {
  if (threadIdx.x == 0 && blockIdx.x == 0) {
    const double m = *loss_accum / (double)((size_t)NROWS * DDIM);
    const float el = (float)m;
    float* tail = out + (size_t)NROWS * DDIM + NROWS;
    tail[0] = 0.25f * el;  // vq_loss = COMMITMENT_COST * e_latent_loss
    tail[1] = el;          // e_latent_loss
    tail[2] = 0.0f;        // codebook_loss
  }
}

extern "C" void kernel_launch(void* const* d_in, const int* in_sizes, int n_in,
                              void* d_out, int out_size, void* d_ws, size_t ws_size,
                              hipStream_t stream) {
  const float* x   = (const float*)d_in[0];  // [N, 64]
  const float* emb = (const float*)d_in[1];  // [K, 64]
  float* out = (float*)d_out;

  char* ws = (char*)d_ws;
  double* loss_accum = (double*)(ws + WS_LOSS);
  float*  se         = (float*)(ws + WS_SE);
  float*  bval       = (float*)(ws + WS_BVAL);
  int*    bidx       = (int*)(ws + WS_BIDX);

  vq_prep<<<KCODES / 256, 256, 0, stream>>>(emb, se, loss_accum);
  vq_argmin<<<(NROWS / 256) * KPART, 256, 0, stream>>>(x, emb, se, bval, bidx);
  vq_finalize<<<NROWS / 256, 256, 0, stream>>>(x, emb, bval, bidx, out, loss_accum);
  vq_scalars<<<1, 64, 0, stream>>>(loss_accum, out);
}

// Round 3
// 181.348 us; speedup vs baseline: 1.0429x; 1.0406x over previous
//
#include <hip/hip_runtime.h>
#include <math.h>

// VQ-VAE VectorQuantizer: B=32,T=2048,D=64,K=1024  -> N=65536 rows.
// Outputs (flat f32 in d_out): quantized_st [N*64], indices [N], vq_loss,
// e_latent_loss, codebook_loss.
//
// Round 3: same exact-fp32 numpy-emulating semantics as rounds 1-2 (absmax
// 0.0), restructured for register pressure. Rounds 1-2 showed VGPR_Count=40
// (xv[64] demoted to AGPRs; 2.26 VALU slots per FMA; launch_bounds ignored).
// New inner loop: NT=16 codes per tile with acc[16]; the x-row is streamed in
// 4x16-float chunks RE-LOADED from L1/L2 per tile instead of held live.
// Live set ~45 VGPR -> fits the default 64-VGPR budget structurally; 16
// independent FMA chains give ample ILP (no serial 256-cyc chain).
// Rounding order per code is UNCHANGED: sequential d=0..63 fmaf chain.

namespace {
constexpr int NROWS = 65536;
constexpr int DDIM  = 64;
constexpr int KCODES = 1024;
constexpr int KPART = 4;
constexpr int CPP = KCODES / KPART;   // codes per partition = 256
constexpr int NT  = 16;               // codes per tile
constexpr int DC  = 16;               // d-chunk size (4 float4 loads)

// ws layout (bytes)
constexpr size_t WS_LOSS = 0;                                   // double
constexpr size_t WS_SE   = 256;                                 // float[K]
constexpr size_t WS_BVAL = 8192;                                // float[KPART*N]
constexpr size_t WS_BIDX = WS_BVAL + (size_t)KPART * NROWS * 4; // int[KPART*N]
}

// ---------------- prep: se[j] = np.sum(e*e, axis=1) (numpy pairwise), zero loss
__global__ __launch_bounds__(256) void vq_prep(const float* __restrict__ emb,
                                               float* __restrict__ se,
                                               double* __restrict__ loss_accum) {
  #pragma clang fp contract(off)
  const int t = blockIdx.x * 256 + threadIdx.x;
  if (t == 0) *loss_accum = 0.0;
  if (t < KCODES) {
    const float* e = emb + (size_t)t * DDIM;
    float r[8];
    #pragma unroll
    for (int j = 0; j < 8; ++j) r[j] = e[j] * e[j];
    #pragma unroll
    for (int i = 8; i < DDIM; i += 8) {
      #pragma unroll
      for (int j = 0; j < 8; ++j) r[j] += e[i + j] * e[i + j];
    }
    se[t] = ((r[0] + r[1]) + (r[2] + r[3])) + ((r[4] + r[5]) + (r[6] + r[7]));
  }
}

// ---------------- main: per-row argmin over a K/4 partition, code-tiled
__global__ __launch_bounds__(256) void vq_argmin(const float* __restrict__ x,
                                                 const float* __restrict__ emb,
                                                 const float* __restrict__ se,
                                                 float* __restrict__ bval,
                                                 int* __restrict__ bidx) {
  #pragma clang fp contract(off)
  const int part = blockIdx.x & (KPART - 1);
  const int rowgroup = blockIdx.x >> 2;
  const int row = rowgroup * 256 + (int)threadIdx.x;

  const float*  xr  = x + (size_t)row * DDIM;
  const float4* xr4 = reinterpret_cast<const float4*>(xr);

  // ||x||^2, numpy pairwise 8-accumulator order, streamed (only 8+8 live).
  float r[8];
  {
    const float4 a = xr4[0], b = xr4[1];
    r[0] = a.x * a.x; r[1] = a.y * a.y; r[2] = a.z * a.z; r[3] = a.w * a.w;
    r[4] = b.x * b.x; r[5] = b.y * b.y; r[6] = b.z * b.z; r[7] = b.w * b.w;
  }
  #pragma unroll
  for (int i = 2; i < 16; i += 2) {
    const float4 a = xr4[i], b = xr4[i + 1];
    r[0] += a.x * a.x; r[1] += a.y * a.y; r[2] += a.z * a.z; r[3] += a.w * a.w;
    r[4] += b.x * b.x; r[5] += b.y * b.y; r[6] += b.z * b.z; r[7] += b.w * b.w;
  }
  const float sx = ((r[0] + r[1]) + (r[2] + r[3])) + ((r[4] + r[5]) + (r[6] + r[7]));

  float best = INFINITY;
  int   bi   = 0;
  const int j0 = part * CPP;

  for (int ct = 0; ct < CPP; ct += NT) {   // 16 tiles of 16 codes
    float acc[NT];
    #pragma unroll
    for (int c = 0; c < NT; ++c) acc[c] = 0.0f;

    #pragma unroll
    for (int ch = 0; ch < DDIM / DC; ++ch) {        // 4 chunks of 16 d
      // re-load this 16-float chunk of the x row (L1/L2-resident)
      float xq[DC];
      #pragma unroll
      for (int q = 0; q < DC / 4; ++q) {
        const float4 v = xr4[ch * (DC / 4) + q];
        xq[q * 4 + 0] = v.x; xq[q * 4 + 1] = v.y;
        xq[q * 4 + 2] = v.z; xq[q * 4 + 3] = v.w;
      }
      #pragma unroll
      for (int c = 0; c < NT; ++c) {
        // wave-uniform address -> scalar loads
        const float* ep = emb + (size_t)(j0 + ct + c) * DDIM + ch * DC;
        float a = acc[c];
        #pragma unroll
        for (int d = 0; d < DC; ++d) a = __builtin_fmaf(xq[d], ep[d], a);
        acc[c] = a;
      }
    }

    #pragma unroll
    for (int c = 0; c < NT; ++c) {                  // ascending j: first-min
      const int j = j0 + ct + c;
      const float T = sx + se[j];                        // fl(sx + se_j)
      const float dist = __builtin_fmaf(-2.0f, acc[c], T); // fl(T - 2*acc)
      if (dist < best) { best = dist; bi = j; }
    }
  }
  bval[(size_t)part * NROWS + row] = best;
  bidx[(size_t)part * NROWS + row] = bi;
}

// ---------------- finalize: combine partitions, gather, ST output, loss
__global__ __launch_bounds__(256) void vq_finalize(const float* __restrict__ x,
                                                   const float* __restrict__ emb,
                                                   const float* __restrict__ bval,
                                                   const int* __restrict__ bidx,
                                                   float* __restrict__ out,
                                                   double* __restrict__ loss_accum) {
  #pragma clang fp contract(off)
  const int row = blockIdx.x * 256 + (int)threadIdx.x;

  float best = bval[row];
  int   bi   = bidx[row];
  #pragma unroll
  for (int p = 1; p < KPART; ++p) {
    const float v = bval[(size_t)p * NROWS + row];
    const int   i = bidx[(size_t)p * NROWS + row];
    if (v < best) { best = v; bi = i; }  // ties keep lower partition (lower j)
  }

  const float* xr = x + (size_t)row * DDIM;
  const float* ep = emb + (size_t)bi * DDIM;
  float* orow = out + (size_t)row * DDIM;
  float lsum = 0.0f;
  #pragma unroll
  for (int d = 0; d < DDIM; ++d) {
    const float xd = xr[d];
    const float q  = ep[d];
    const float diff = q - xd;     // fl(q - x)
    orow[d] = xd + diff;           // straight-through: fl(x + fl(q - x))
    lsum += diff * diff;           // (q - x)^2, order-insensitive (2% thr)
  }

  out[(size_t)NROWS * DDIM + row] = (float)bi;  // index as f32 (exact <= 1023)

  #pragma unroll
  for (int off = 32; off > 0; off >>= 1) lsum += __shfl_down(lsum, off, 64);
  if ((threadIdx.x & 63) == 0) atomicAdd(loss_accum, (double)lsum);
}

// ---------------- scalars
__global__ void vq_scalars(const double* __restrict__ loss_accum,
                           float* __restrict__ out) {
  if (threadIdx.x == 0 && blockIdx.x == 0) {
    const double m = *loss_accum / (double)((size_t)NROWS * DDIM);
    const float el = (float)m;
    float* tail = out + (size_t)NROWS * DDIM + NROWS;
    tail[0] = 0.25f * el;  // vq_loss = COMMITMENT_COST * e_latent_loss
    tail[1] = el;          // e_latent_loss
    tail[2] = 0.0f;        // codebook_loss
  }
}

extern "C" void kernel_launch(void* const* d_in, const int* in_sizes, int n_in,
                              void* d_out, int out_size, void* d_ws, size_t ws_size,
                              hipStream_t stream) {
  const float* x   = (const float*)d_in[0];  // [N, 64]
  const float* emb = (const float*)d_in[1];  // [K, 64]
  float* out = (float*)d_out;

  char* ws = (char*)d_ws;
  double* loss_accum = (double*)(ws + WS_LOSS);
  float*  se         = (float*)(ws + WS_SE);
  float*  bval       = (float*)(ws + WS_BVAL);
  int*    bidx       = (int*)(ws + WS_BIDX);

  vq_prep<<<KCODES / 256, 256, 0, stream>>>(emb, se, loss_accum);
  vq_argmin<<<(NROWS / 256) * KPART, 256, 0, stream>>>(x, emb, se, bval, bidx);
  vq_finalize<<<NROWS / 256, 256, 0, stream>>>(x, emb, bval, bidx, out, loss_accum);
  vq_scalars<<<1, 64, 0, stream>>>(loss_accum, out);
}